// Round 11
// baseline (285.665 us; speedup 1.0000x reference)
//
#include <hip/hip_runtime.h>
#include <hip/hip_fp16.h>

// TGCN forward, algebraically reduced (H0 = 0 => R/Wr dead, Z*H = 0):
//   deg[d] = #in-edges of d ; dinv = rsqrt(deg+1)
//   xs[s]  = fp16( x[s] * dinv[s] )   (stored quarter-major: xsq[q][node][16])
//   agg[d] = bf16( dinv[d] * ( sum_{e: dst=d} xs[src] + xs[d]*dinv[d] ) )
//   M = [Wz@Lzw_top | Wh@Lhw_top]  (64x512, bf16, MFMA B-layout), cb = bias fold
//   out = softmax(relu((1-Z)*Ht) @ Wo + bo)
//
// R1 -> R2: atomic scatter (2700us) -> CSR build + register gather.
// R3 -> R4: scatter write amp -> 2-level bucket sort (793 -> 455us).
// R7 -> R8: node GEMM -> mfma_f32_16x16x32_bf16 (412 -> off top-5).
// R14 -> R15: epilogue fp32 divides -> v_rcp_f32 (304 -> 275.7).
// R16: launch-count fusion NEUTRAL: graph capture amortizes launches.
// R17: LDS ds_add_f32 per-edge accumulation DISASTER (1339us). Lesson:
//   LDS atomics only as occasional ops, never the per-element primitive.
// R18: deg via 3.2M scattered global atomics = 130us. Occasional only.
// R19: LDS-resident csr gather + LDS-histogram deg. 264.5us.
// R20: mega-fusion FAILED (367) but gave attribution (front-end ~176).
// R21: bucket-strided preallocation front-end. 252.1us.
// R22: LDS tile-sort + coalesced run copies; SHIFT 7. 249.5us.
// R23: build_m float4 W rows + 16-lane run copies. 238.4us best.
// R24: XCD-pinned channel-quarter gather. Cache theory RIGHT (FETCH
//   150.6 -> 46.6MB) but lost to scan/copy/reduce overhead (130.8us).
// R25: overhead stripped (92.9us) but still latency-bound: direct-global
//   csr -> xq is a 2-deep ~400cy dependent chain, VALUBusy 26%, occ 69%.
//   FETCH 78.8MB = 51.2 csr x4 + ~27 quarter-table L2-thrash refetch.
// R25 -> R26 (last attempt, pre-committed): csr window -> LDS via
//   NONTEMPORAL loads (breaks chain link 1; nt protects table residency),
//   depth-2 software pipeline on xq loads (overlaps link 2), LDS 20.5KB
//   -> 4 blocks/CU = 32 waves (TLP +45%). Falsifier: qg >= 50us or total
//   >= 238.4 -> permanent revert to R23.

#define SHIFT 7
#define NPB   128          // nodes per bucket (=1<<SHIFT)
#define BMAX  1024         // max buckets (n <= 131072 for 17-bit src packing)
#define TILE  8192         // edges per tile (scatter blocks)
#define EPT   16           // edges per thread in a tile (TILE/512)
#define MBBLK 64           // fused build_m blocks (512 j-cols / 8 per block)
#define CAPB  5120         // staging/csr slots per bucket (mean 4096, sd 64)

typedef __attribute__((ext_vector_type(8))) short short8;
typedef __attribute__((ext_vector_type(4))) float floatx4;

__device__ __forceinline__ ushort f2b(float f) {   // fp32 -> bf16 RNE
    union { float f; unsigned u; } v; v.f = f;
    unsigned r = v.u + 0x7FFFu + ((v.u >> 16) & 1u);
    return (ushort)(r >> 16);
}

__device__ __forceinline__ float fastrcp(float x) {  // v_rcp_f32, ~1e-5 rel err
    return __builtin_amdgcn_rcpf(x);
}

// blocks [0,nT): per-tile: dsts -> regs + LDS hist; 1024-wide block scan;
//   block-granular global reserve; counting-sort tile into LDS `sorted`;
//   16-lane-group coalesced run copies into staging[b*CAPB + gbase + .].
// blocks [nT,nT+MBBLK): weight fold  Mb[j][k] = bf16(sum_t W[k][t]*L[t][j])
__global__ __launch_bounds__(512) void scatter_build_kernel(
    const int* __restrict__ srcs, const int* __restrict__ dsts,
    int* __restrict__ gcur, int* __restrict__ staging, int E, int B, int nT,
    const float* __restrict__ Wz, const float* __restrict__ bz,
    const float* __restrict__ Wh, const float* __restrict__ bh,
    const float* __restrict__ Lzw, const float* __restrict__ Lzb,
    const float* __restrict__ Lhw, const float* __restrict__ Lhb,
    ushort* __restrict__ Mb, float* __restrict__ cb) {
    __shared__ int cnt[BMAX];     // per-bucket tile count
    __shared__ int ssum[BMAX];    // inclusive scan of cnt
    __shared__ int gbase[BMAX];   // global reserved base
    __shared__ int cur[BMAX];     // LDS scatter cursor (local offset)
    __shared__ int sorted[TILE];  // tile payloads sorted by bucket (32KB)
    if (blockIdx.x < nT) {
        int tid = threadIdx.x;
        for (int i = tid; i < BMAX; i += 512) cnt[i] = 0;
        __syncthreads();
        int tile0 = blockIdx.x * TILE;
        int dreg[EPT];
#pragma unroll
        for (int j = 0; j < EPT; ++j) {
            int e = tile0 + j * 512 + tid;
            dreg[j] = (e < E) ? dsts[e] : -1;
            if (dreg[j] >= 0) atomicAdd(&cnt[((unsigned)dreg[j]) >> SHIFT], 1);
        }
        __syncthreads();
        // inclusive 1024-wide Hillis-Steele scan (2 elems/thread)
        {
            int i0 = tid, i1 = tid + 512;
            ssum[i0] = cnt[i0];
            ssum[i1] = cnt[i1];
            __syncthreads();
            for (int off = 1; off < BMAX; off <<= 1) {
                int t0 = (i0 >= off) ? ssum[i0 - off] : 0;
                int t1 = (i1 >= off) ? ssum[i1 - off] : 0;
                __syncthreads();
                ssum[i0] += t0;
                ssum[i1] += t1;
                __syncthreads();
            }
        }
        for (int i = tid; i < BMAX; i += 512) {
            int c = cnt[i];
            gbase[i] = (c > 0) ? atomicAdd(&gcur[i], c) : 0;   // reserve
            cur[i] = ssum[i] - c;                              // local base
        }
        __syncthreads();
        // counting-sort the tile into LDS (scattered stores -> LDS only)
#pragma unroll
        for (int j = 0; j < EPT; ++j) {
            int d = dreg[j];
            if (d >= 0) {
                int e = tile0 + j * 512 + tid;
                int s = srcs[e];
                int b = ((unsigned)d) >> SHIFT;
                int pos = atomicAdd(&cur[b], 1);
                sorted[pos] = ((d & (NPB - 1)) << 17) | s;
            }
        }
        __syncthreads();
        // 16-lane-group coalesced run copy to global staging (runs ~10.5)
        int grp = tid >> 4, l16 = tid & 15;     // 32 groups of 16 lanes
        for (int b = grp; b < B; b += 32) {
            int c = cnt[b];
            if (c == 0) continue;
            int lb = ssum[b] - c;
            int gb = gbase[b];
            size_t gp = (size_t)b * CAPB + gb;
            for (int j = l16; j < c; j += 16)
                if (gb + j < CAPB) staging[gp + j] = sorted[lb + j];
        }
    } else {
        int j = (blockIdx.x - nT) * 8 + (threadIdx.x >> 6);   // 0..511
        int k = threadIdx.x & 63;                             // 0..63
        int which = j >> 8;
        int jj = j & 255;
        const float* W  = which ? Wh  : Wz;
        const float* bv = which ? bh  : bz;
        const float* L  = which ? Lhw : Lzw;   // [512,256]; rows 0..255 (H0=0)
        const float* Lb = which ? Lhb : Lzb;
        const float4* Wr = (const float4*)(W + k * 256);
        float acc = 0.f;
        for (int t4 = 0; t4 < 64; ++t4) {
            float4 wv = Wr[t4];
            int t = t4 * 4;
            acc = fmaf(wv.x, L[(t + 0) * 256 + jj], acc);
            acc = fmaf(wv.y, L[(t + 1) * 256 + jj], acc);
            acc = fmaf(wv.z, L[(t + 2) * 256 + jj], acc);
            acc = fmaf(wv.w, L[(t + 3) * 256 + jj], acc);
        }
        Mb[j * 64 + k] = f2b(acc);
        if (k == 0) {
            float a = 0.f;
            for (int t = 0; t < 256; ++t) a = fmaf(bv[t], L[t * 256 + jj], a);
            cb[j] = a + Lb[jj];
        }
    }
}

// one block per 128-node bucket:
//   A) histogram window -> deg/dinv/startg (LDS atomics, occasional class)
//   B) counting-sort window into LDS csrl, linear writeback -> csr
//   C) xs_q write: xsq[q][node][16 halfs] quarter-major (dinv from LDS)
__global__ __launch_bounds__(512) void prep_sort_kernel(
    const int* __restrict__ staging,
    const int* __restrict__ gcur,
    const float* __restrict__ x,
    int* __restrict__ deg,
    int* __restrict__ startg,
    int* __restrict__ csr,
    __half* __restrict__ xsq,
    int n, int B) {
    int b = blockIdx.x;
    int tid = threadIdx.x;
    __shared__ int   nd[NPB];
    __shared__ int   ssc[NPB];
    __shared__ int   ncur[NPB];
    __shared__ float sdinv[NPB];
    __shared__ int   csrl[CAPB];
    if (tid < NPB) nd[tid] = 0;
    __syncthreads();
    int count = gcur[b];
    if (count > CAPB) count = CAPB;
    size_t base = (size_t)b * CAPB;
    for (int i = tid; i < count; i += 512)
        atomicAdd(&nd[staging[base + i] >> 17], 1);
    __syncthreads();
    int d0 = 0;
    if (tid < NPB) { d0 = nd[tid]; ssc[tid] = d0; }
    __syncthreads();
    for (int off = 1; off < NPB; off <<= 1) {
        int t = 0;
        if (tid < NPB && tid >= off) t = ssc[tid - off];
        __syncthreads();
        if (tid < NPB) ssc[tid] += t;
        __syncthreads();
    }
    if (tid < NPB) {
        int excl = ssc[tid] - d0;
        ncur[tid] = excl;
        float dn = rsqrtf((float)d0 + 1.0f);
        sdinv[tid] = dn;
        int node = (b << SHIFT) + tid;
        if (node < n) {
            deg[node] = d0;
            startg[node] = excl;    // local offset within bucket window
        }
    }
    __syncthreads();
    for (int i = tid; i < count; i += 512) {
        int p = staging[base + i];
        int pos = atomicAdd(&ncur[p >> 17], 1);
        if (pos < CAPB) csrl[pos] = p & 0x1FFFF;
    }
    __syncthreads();
    for (int i = tid; i < count; i += 512)       // linear, coalesced
        csr[base + i] = csrl[i];
    // xs_q: quarter-major fp16 rows
    int nbase = b << SHIFT;
    for (int i2 = tid; i2 < NPB * 16; i2 += 512) {
        int nl = i2 >> 4;
        int g  = i2 & 15;                         // ch group (4 floats)
        int node = nbase + nl;
        if (node < n) {
            float dn = sdinv[nl];
            float4 vx = ((const float4*)x)[(size_t)node * 16 + g];
            __half2 a  = __floats2half2_rn(vx.x * dn, vx.y * dn);
            __half2 c2 = __floats2half2_rn(vx.z * dn, vx.w * dn);
            int q = g >> 2;
            size_t off = ((size_t)q * n + node) * 16 + (size_t)(g & 3) * 4;
            *(__half2*)(xsq + off)     = a;
            *(__half2*)(xsq + off + 2) = c2;
        }
    }
}

// 8*ceil(B/2) blocks; quarter q = (blk&7)>>1 pinned to an XCD pair via the
// blk%8 round-robin (R24-verified); bucket b = (blk>>3)*2 + (blk&1).
// csr window -> LDS via NONTEMPORAL loads (no L2 pollution of the 3.2MB
// quarter table). Wave = 16 nodes as 4 groups of 4: lane = ns(0..3) x
// eg(0..7) x c(0..1). Depth-2 software-pipelined xq loads. 3-level reduce.
__global__ __launch_bounds__(512) void quarter_gather_kernel(
    const int* __restrict__ csr,
    const int* __restrict__ startg,
    const int* __restrict__ deg,
    const __half* __restrict__ xsq,
    ushort* __restrict__ aggb, int n, int B) {
    int blk = blockIdx.x;
    int xcd = blk & 7;
    int q   = xcd >> 1;
    int b   = ((blk >> 3) << 1) | (xcd & 1);
    if (b >= B) return;
    int tid = threadIdx.x;
    __shared__ int   csrl[CAPB];
    __shared__ int   sstart[NPB];
    __shared__ int   sdeg[NPB];
    __shared__ float sdinv[NPB];
    int node0 = b << SHIFT;
    if (tid < NPB) {
        int nodeid = node0 + tid;
        int dg = (nodeid < n) ? deg[nodeid] : 0;
        sdeg[tid]   = dg;
        sstart[tid] = (nodeid < n) ? startg[nodeid] : 0;
        sdinv[tid]  = rsqrtf((float)dg + 1.0f);
    }
    {   // coalesced nontemporal window copy (bypass-ish: protect L2 table)
        const int* csrb = csr + (size_t)b * CAPB;
        for (int i = tid; i < CAPB; i += 512)
            csrl[i] = __builtin_nontemporal_load(&csrb[i]);
    }
    __syncthreads();
    const __half* xq = xsq + (size_t)q * n * 16;   // this quarter's table
    int wv = tid >> 6, lane = tid & 63;
    int ns = lane >> 4;          // node slot in group 0..3
    int eg = (lane >> 1) & 7;    // edge group 0..7
    int c  = lane & 1;           // 16B chunk of the 32B quarter row
    for (int grp = 0; grp < 4; ++grp) {
        int nl   = (wv << 4) + (grp << 2) + ns;
        int node = node0 + nl;
        int s0 = sstart[nl];
        int d  = sdeg[nl];
        __half2 hz = __float2half2_rn(0.f);
        __half2 hacc[4] = {hz, hz, hz, hz};
        int nb8 = (d & ~7) >> 3;                 // full 8-edge batches
        // depth-2 software pipeline over batches
        uint4 pA, pB;
        if (nb8 >= 1) {
            int idx = csrl[s0 + eg];
            pA = *(const uint4*)(xq + (size_t)idx * 16 + c * 8);
        }
        if (nb8 >= 2) {
            int idx = csrl[s0 + 8 + eg];
            pB = *(const uint4*)(xq + (size_t)idx * 16 + c * 8);
        }
        for (int i = 2; i < nb8; ++i) {
            int idx = csrl[s0 + i * 8 + eg];
            uint4 pC = *(const uint4*)(xq + (size_t)idx * 16 + c * 8);
            union { uint4 u; __half2 h[4]; } p; p.u = pA;
#pragma unroll
            for (int t = 0; t < 4; ++t) hacc[t] = __hadd2(hacc[t], p.h[t]);
            pA = pB; pB = pC;
        }
        if (nb8 >= 2) {
            union { uint4 u; __half2 h[4]; } p; p.u = pA;
#pragma unroll
            for (int t = 0; t < 4; ++t) hacc[t] = __hadd2(hacc[t], p.h[t]);
            pA = pB;
        }
        if (nb8 >= 1) {
            union { uint4 u; __half2 h[4]; } p; p.u = pA;
#pragma unroll
            for (int t = 0; t < 4; ++t) hacc[t] = __hadd2(hacc[t], p.h[t]);
        }
        int full = nb8 << 3;
        if (full < d) {                          // single ragged tail
            int e = full + eg;
            int idx = csrl[s0 + (e < d ? e : 0)];
            union { uint4 u; __half2 h[4]; } p;
            p.u = *(const uint4*)(xq + (size_t)idx * 16 + c * 8);
            if (e >= d) p.u = make_uint4(0u, 0u, 0u, 0u);
#pragma unroll
            for (int t = 0; t < 4; ++t) hacc[t] = __hadd2(hacc[t], p.h[t]);
        }
        // reduce eg 8->1 within each node's 16 lanes (covers 4 nodes/instr)
#pragma unroll
        for (int off = 8; off >= 2; off >>= 1) {
#pragma unroll
            for (int t = 0; t < 4; ++t) {
                union { __half2 h; int i; } u;
                u.h = hacc[t];
                u.i = __shfl_down(u.i, off);
                hacc[t] = __hadd2(hacc[t], u.h);
            }
        }
        if (eg == 0 && node < n) {
            float dn = sdinv[nl];
            union { uint4 u; __half2 h[4]; } p;
            p.u = *(const uint4*)(xq + (size_t)node * 16 + c * 8);
            uint4 o;
            unsigned* ow = (unsigned*)&o;
#pragma unroll
            for (int t = 0; t < 4; ++t) {
                float2 a = __half22float2(hacc[t]);
                float2 f = __half22float2(p.h[t]);
                float v0 = dn * fmaf(f.x, dn, a.x);
                float v1 = dn * fmaf(f.y, dn, a.y);
                ow[t] = (unsigned)f2b(v0) | ((unsigned)f2b(v1) << 16);
            }
            *(uint4*)(aggb + (size_t)node * 64 + q * 16 + c * 8) = o;
        }
    }
}

// 512 threads = 8 waves. Wave w owns cols w*32..w*32+31 for BOTH gates
// (z and ht meet in-register, h=relu((1-z)*ht) -> one h-plane in LDS).
__global__ __launch_bounds__(512) void node_mfma_kernel(
    const ushort* __restrict__ aggb,   // [n][64] bf16
    const ushort* __restrict__ Mb,     // [512][64] bf16 (B layout)
    const float* __restrict__ cb,      // [512]
    const float* __restrict__ Wo, const float* __restrict__ bo,
    float* __restrict__ out, int n) {
    int tid  = threadIdx.x;
    int w    = tid >> 6;
    int lane = tid & 63;
    int nidx = lane & 15;
    int quad = lane >> 4;
    short8 bfz[2][2], bfh[2][2];
    float cbz[2], cbh[2];
#pragma unroll
    for (int cg = 0; cg < 2; ++cg) {
        int colZ = (w << 5) + (cg << 4) + nidx;
        int colH = 256 + colZ;
#pragma unroll
        for (int s = 0; s < 2; ++s) {
            bfz[cg][s] = *(const short8*)(Mb + colZ * 64 + s * 32 + quad * 8);
            bfh[cg][s] = *(const short8*)(Mb + colH * 64 + s * 32 + quad * 8);
        }
        cbz[cg] = cb[colZ];
        cbh[cg] = cb[colH];
    }
    __shared__ float sH[32][260];    // 33 KB h-plane (260 pad: 2-way on stores)
    __shared__ float sWo[4][256];
    if (tid < 256) {
#pragma unroll
        for (int o = 0; o < 4; ++o) sWo[o][tid] = Wo[tid * 4 + o];
    }
    float bo0 = bo[0], bo1 = bo[1], bo2 = bo[2], bo3 = bo[3];
    int ntiles = (n + 31) >> 5;
    for (int tile = blockIdx.x; tile < ntiles; tile += gridDim.x) {
        int node0 = tile << 5;
        int nA0 = node0 + nidx;
        int nA1 = node0 + 16 + nidx;
        if (nA0 >= n) nA0 = n - 1;   // clamp; stores are guarded
        if (nA1 >= n) nA1 = n - 1;
        const ushort* ar0 = aggb + (size_t)nA0 * 64;
        const ushort* ar1 = aggb + (size_t)nA1 * 64;
        short8 a00 = *(const short8*)(ar0 + quad * 8);
        short8 a01 = *(const short8*)(ar0 + 32 + quad * 8);
        short8 a10 = *(const short8*)(ar1 + quad * 8);
        short8 a11 = *(const short8*)(ar1 + 32 + quad * 8);
#pragma unroll
        for (int cg = 0; cg < 2; ++cg) {
            int col = (w << 5) + (cg << 4) + nidx;
#pragma unroll
            for (int grp = 0; grp < 2; ++grp) {
                short8 a0 = grp ? a10 : a00;
                short8 a1 = grp ? a11 : a01;
                floatx4 cz = {cbz[cg], cbz[cg], cbz[cg], cbz[cg]};
                cz = __builtin_amdgcn_mfma_f32_16x16x32_bf16(a0, bfz[cg][0], cz, 0, 0, 0);
                cz = __builtin_amdgcn_mfma_f32_16x16x32_bf16(a1, bfz[cg][1], cz, 0, 0, 0);
                floatx4 chh = {cbh[cg], cbh[cg], cbh[cg], cbh[cg]};
                chh = __builtin_amdgcn_mfma_f32_16x16x32_bf16(a0, bfh[cg][0], chh, 0, 0, 0);
                chh = __builtin_amdgcn_mfma_f32_16x16x32_bf16(a1, bfh[cg][1], chh, 0, 0, 0);
#pragma unroll
                for (int r = 0; r < 4; ++r) {
                    int row = (grp << 4) + (quad << 2) + r;   // node within tile
                    float zc = fastrcp(1.0f + __expf(cz[r]));     // 1 - sigmoid
                    float th = 1.0f - 2.0f * fastrcp(1.0f + __expf(2.0f * chh[r]));
                    sH[row][col] = fmaxf(zc * th, 0.0f);
                }
            }
        }
        __syncthreads();
        {   // head: 16 threads per node, 16 channels each
            int nb = tid >> 4, g = tid & 15;
            float l0 = 0.f, l1 = 0.f, l2 = 0.f, l3 = 0.f;
#pragma unroll
            for (int ii = 0; ii < 16; ++ii) {
                int ch = g + 16 * ii;
                float hv = sH[nb][ch];
                l0 = fmaf(hv, sWo[0][ch], l0);
                l1 = fmaf(hv, sWo[1][ch], l1);
                l2 = fmaf(hv, sWo[2][ch], l2);
                l3 = fmaf(hv, sWo[3][ch], l3);
            }
#pragma unroll
            for (int off = 8; off > 0; off >>= 1) {
                l0 += __shfl_down(l0, off, 16);
                l1 += __shfl_down(l1, off, 16);
                l2 += __shfl_down(l2, off, 16);
                l3 += __shfl_down(l3, off, 16);
            }
            int node = node0 + nb;
            if (g == 0 && node < n) {
                float v0 = l0 + bo0, v1 = l1 + bo1, v2 = l2 + bo2, v3 = l3 + bo3;
                float mx = fmaxf(fmaxf(v0, v1), fmaxf(v2, v3));
                float e0 = __expf(v0 - mx), e1 = __expf(v1 - mx);
                float e2 = __expf(v2 - mx), e3 = __expf(v3 - mx);
                float inv = fastrcp(e0 + e1 + e2 + e3);
                float4 o;
                o.x = e0 * inv; o.y = e1 * inv; o.z = e2 * inv; o.w = e3 * inv;
                ((float4*)out)[node] = o;
            }
        }
        __syncthreads();
    }
}

extern "C" void kernel_launch(void* const* d_in, const int* in_sizes, int n_in,
                              void* d_out, int out_size, void* d_ws, size_t ws_size,
                              hipStream_t stream) {
    const float* x   = (const float*)d_in[0];
    const int*  eidx = (const int*)d_in[1];
    const float* Wz  = (const float*)d_in[2];
    const float* bz  = (const float*)d_in[3];
    // d_in[4]=Wr, d_in[5]=br : dead (H0 = 0)
    const float* Wh  = (const float*)d_in[6];
    const float* bh  = (const float*)d_in[7];
    const float* Lzw = (const float*)d_in[8];
    const float* Lzb = (const float*)d_in[9];
    // d_in[10]=Lrw, d_in[11]=Lrb : dead
    const float* Lhw = (const float*)d_in[12];
    const float* Lhb = (const float*)d_in[13];
    const float* Wo  = (const float*)d_in[14];
    const float* bo  = (const float*)d_in[15];
    float* out = (float*)d_out;

    int n = in_sizes[0] / 64;
    int E = in_sizes[1] / 2;
    const int* srcs = eidx;
    const int* dsts = eidx + E;
    int B = (n + NPB - 1) >> SHIFT;
    int nT = (E + TILE - 1) / TILE;

    size_t na = ((size_t)n + 3) & ~(size_t)3;
    size_t bucketArr = (((size_t)B * CAPB * 4) + 255) & ~(size_t)255;
    size_t aggBytes  = (((size_t)n * 64 * 2) + 255) & ~(size_t)255;

    char* ws = (char*)d_ws;
    int*   deg    = (int*)ws;    ws += na * 4;
    int*   startg = (int*)ws;    ws += na * 4;
    int*   gcur   = (int*)ws;    ws += BMAX * 4;
    int*   staging = (int*)ws;   ws += bucketArr;       // live through prep_sort
    int*   csr    = (int*)ws;    ws += bucketArr;       // live through gather
    __half* xsq   = (__half*)ws; ws += (size_t)n * 64 * 2;
    ushort* aggb  = (ushort*)ws; ws += aggBytes;
    ushort* Mb    = (ushort*)ws; ws += 512 * 64 * 2;
    float* cb     = (float*)ws;  ws += 512 * 4;

    hipMemsetAsync(gcur, 0, BMAX * 4, stream);
    scatter_build_kernel<<<nT + MBBLK, 512, 0, stream>>>(srcs, dsts, gcur,
                                                         staging, E, B, nT,
                                                         Wz, bz, Wh, bh,
                                                         Lzw, Lzb, Lhw, Lhb,
                                                         Mb, cb);
    prep_sort_kernel<<<B, 512, 0, stream>>>(staging, gcur, x, deg, startg,
                                            csr, xsq, n, B);
    int gq = 8 * ((B + 1) / 2);
    quarter_gather_kernel<<<gq, 512, 0, stream>>>(csr, startg, deg, xsq,
                                                  aggb, n, B);
    node_mfma_kernel<<<1024, 512, 0, stream>>>(aggb, Mb, cb, Wo, bo, out, n);
}

// Round 12
// 238.315 us; speedup vs baseline: 1.1987x; 1.1987x over previous
//
#include <hip/hip_runtime.h>
#include <hip/hip_fp16.h>

// TGCN forward, algebraically reduced (H0 = 0 => R/Wr dead, Z*H = 0):
//   deg[d] = #in-edges of d ; dinv = rsqrt(deg+1)
//   xs[s]  = fp16( x[s] * dinv[s] )
//   agg[d] = bf16( dinv[d] * ( sum_{e: dst=d} xs[src] + xs[d]*dinv[d] ) )
//   M = [Wz@Lzw_top | Wh@Lhw_top]  (64x512, bf16, MFMA B-layout), cb = bias fold
//   out = softmax(relu((1-Z)*Ht) @ Wo + bo)
//
// R1 -> R2: atomic scatter (2700us) -> CSR build + register gather.
// R3 -> R4: scatter write amp -> 2-level bucket sort (793 -> 455us).
// R7 -> R8: node GEMM -> mfma_f32_16x16x32_bf16 (412 -> off top-5).
// R14 -> R15: epilogue fp32 divides -> v_rcp_f32 (304 -> 275.7).
// R16: launch-count fusion NEUTRAL: graph capture amortizes launches.
// R17: LDS ds_add_f32 per-edge accumulation DISASTER (1339us). Lesson:
//   LDS atomics only as occasional ops, never the per-element primitive.
// R18: deg via 3.2M scattered global atomics = 130us. Lesson: device-scope
//   scattered atomics are memory-side round trips; occasional only.
// R19: LDS-resident csr gather + LDS-histogram deg. 264.5us.
// R20: mega-fusion of node_mfma into gather FAILED (367): LDS-occupancy
//   crush + shfl/LDS-pipe head serialization. Reverted; gave attribution.
// R21: bucket-strided preallocation front-end. 252.1us.
// R22: LDS tile-sort + coalesced run copies; SHIFT 7. 249.5us.
// R23: build_m float4 W rows + 16-lane run copies. 238.4us == CURRENT BEST.
// R24-R26: XCD-pinned channel-quarter gather arc, CLOSED by pre-committed
//   falsifier. Cache mechanism verified (FETCH 150.6 -> 46.6MB, HBM 2.9 ->
//   0.46 TB/s when each XCD's working set fits its 4MB L2) but the
//   structure's fixed costs (x4 csr window traffic, x4 front-matter,
//   32B-row gather granularity, csr->xq latency chain) ate the win in all
//   three implementations (130.8 / 92.9 / 99.7us vs bucket_gather's 56.5).
//   Lesson: L2-residency wins must not multiply index traffic; revert
//   executed, this file is byte-identical to the measured-238.4 R23.

#define SHIFT 7
#define NPB   128          // nodes per bucket (=1<<SHIFT)
#define BMAX  1024         // max buckets (n <= 131072 for 17-bit src packing)
#define TILE  8192         // edges per tile (scatter blocks)
#define EPT   16           // edges per thread in a tile (TILE/512)
#define MBBLK 64           // fused build_m blocks (512 j-cols / 8 per block)
#define CAPB  5120         // staging/csr slots per bucket (mean 4096, sd 64)

typedef __attribute__((ext_vector_type(8))) short short8;
typedef __attribute__((ext_vector_type(4))) float floatx4;

__device__ __forceinline__ ushort f2b(float f) {   // fp32 -> bf16 RNE
    union { float f; unsigned u; } v; v.f = f;
    unsigned r = v.u + 0x7FFFu + ((v.u >> 16) & 1u);
    return (ushort)(r >> 16);
}

__device__ __forceinline__ float fastrcp(float x) {  // v_rcp_f32, ~1e-5 rel err
    return __builtin_amdgcn_rcpf(x);
}

// blocks [0,nT): per-tile: dsts -> regs + LDS hist; 1024-wide block scan;
//   block-granular global reserve; counting-sort tile into LDS `sorted`;
//   16-lane-group coalesced run copies into staging[b*CAPB + gbase + .].
// blocks [nT,nT+MBBLK): weight fold  Mb[j][k] = bf16(sum_t W[k][t]*L[t][j])
__global__ __launch_bounds__(512) void scatter_build_kernel(
    const int* __restrict__ srcs, const int* __restrict__ dsts,
    int* __restrict__ gcur, int* __restrict__ staging, int E, int B, int nT,
    const float* __restrict__ Wz, const float* __restrict__ bz,
    const float* __restrict__ Wh, const float* __restrict__ bh,
    const float* __restrict__ Lzw, const float* __restrict__ Lzb,
    const float* __restrict__ Lhw, const float* __restrict__ Lhb,
    ushort* __restrict__ Mb, float* __restrict__ cb) {
    __shared__ int cnt[BMAX];     // per-bucket tile count
    __shared__ int ssum[BMAX];    // inclusive scan of cnt
    __shared__ int gbase[BMAX];   // global reserved base
    __shared__ int cur[BMAX];     // LDS scatter cursor (local offset)
    __shared__ int sorted[TILE];  // tile payloads sorted by bucket (32KB)
    if (blockIdx.x < nT) {
        int tid = threadIdx.x;
        for (int i = tid; i < BMAX; i += 512) cnt[i] = 0;
        __syncthreads();
        int tile0 = blockIdx.x * TILE;
        int dreg[EPT];
#pragma unroll
        for (int j = 0; j < EPT; ++j) {
            int e = tile0 + j * 512 + tid;
            dreg[j] = (e < E) ? dsts[e] : -1;
            if (dreg[j] >= 0) atomicAdd(&cnt[((unsigned)dreg[j]) >> SHIFT], 1);
        }
        __syncthreads();
        // inclusive 1024-wide Hillis-Steele scan (2 elems/thread)
        {
            int i0 = tid, i1 = tid + 512;
            ssum[i0] = cnt[i0];
            ssum[i1] = cnt[i1];
            __syncthreads();
            for (int off = 1; off < BMAX; off <<= 1) {
                int t0 = (i0 >= off) ? ssum[i0 - off] : 0;
                int t1 = (i1 >= off) ? ssum[i1 - off] : 0;
                __syncthreads();
                ssum[i0] += t0;
                ssum[i1] += t1;
                __syncthreads();
            }
        }
        for (int i = tid; i < BMAX; i += 512) {
            int c = cnt[i];
            gbase[i] = (c > 0) ? atomicAdd(&gcur[i], c) : 0;   // reserve
            cur[i] = ssum[i] - c;                              // local base
        }
        __syncthreads();
        // counting-sort the tile into LDS (scattered stores -> LDS only)
#pragma unroll
        for (int j = 0; j < EPT; ++j) {
            int d = dreg[j];
            if (d >= 0) {
                int e = tile0 + j * 512 + tid;
                int s = srcs[e];
                int b = ((unsigned)d) >> SHIFT;
                int pos = atomicAdd(&cur[b], 1);
                sorted[pos] = ((d & (NPB - 1)) << 17) | s;
            }
        }
        __syncthreads();
        // 16-lane-group coalesced run copy to global staging (runs ~10.5)
        int grp = tid >> 4, l16 = tid & 15;     // 32 groups of 16 lanes
        for (int b = grp; b < B; b += 32) {
            int c = cnt[b];
            if (c == 0) continue;
            int lb = ssum[b] - c;
            int gb = gbase[b];
            size_t gp = (size_t)b * CAPB + gb;
            for (int j = l16; j < c; j += 16)
                if (gb + j < CAPB) staging[gp + j] = sorted[lb + j];
        }
    } else {
        int j = (blockIdx.x - nT) * 8 + (threadIdx.x >> 6);   // 0..511
        int k = threadIdx.x & 63;                             // 0..63
        int which = j >> 8;
        int jj = j & 255;
        const float* W  = which ? Wh  : Wz;
        const float* bv = which ? bh  : bz;
        const float* L  = which ? Lhw : Lzw;   // [512,256]; rows 0..255 (H0=0)
        const float* Lb = which ? Lhb : Lzb;
        // W row via float4: 4 t-steps per line touch (was 64 lines/scalar
        // instr). Same fmaf chain order -> bit-identical to scalar version.
        const float4* Wr = (const float4*)(W + k * 256);
        float acc = 0.f;
        for (int t4 = 0; t4 < 64; ++t4) {
            float4 wv = Wr[t4];
            int t = t4 * 4;
            acc = fmaf(wv.x, L[(t + 0) * 256 + jj], acc);
            acc = fmaf(wv.y, L[(t + 1) * 256 + jj], acc);
            acc = fmaf(wv.z, L[(t + 2) * 256 + jj], acc);
            acc = fmaf(wv.w, L[(t + 3) * 256 + jj], acc);
        }
        Mb[j * 64 + k] = f2b(acc);
        if (k == 0) {
            float a = 0.f;
            for (int t = 0; t < 256; ++t) a = fmaf(bv[t], L[t * 256 + jj], a);
            cb[j] = a + Lb[jj];
        }
    }
}

// one block per 128-node bucket: deg counted from the bucket's staging
// window via LDS histogram atomics, deg written coalesced; then the
// bucket's xs rows: xs[s][c] = fp16(x[s][c]*dinv[s]) (dinv in LDS only).
__global__ __launch_bounds__(512) void prep_kernel(const int* __restrict__ staging,
                                                   const int* __restrict__ gcur,
                                                   const float* __restrict__ x,
                                                   int* __restrict__ deg,
                                                   __half* __restrict__ xs,
                                                   int n, int B) {
    int b = blockIdx.x;
    int tid = threadIdx.x;
    __shared__ int nd[NPB];
    __shared__ float sdinv[NPB];
    if (tid < NPB) nd[tid] = 0;
    __syncthreads();
    int count = gcur[b];
    if (count > CAPB) count = CAPB;
    size_t base = (size_t)b * CAPB;
    for (int i = tid; i < count; i += 512)
        atomicAdd(&nd[staging[base + i] >> 17], 1);
    __syncthreads();
    if (tid < NPB) {
        int dg = nd[tid];
        float dn = rsqrtf((float)dg + 1.0f);
        sdinv[tid] = dn;
        int node = (b << SHIFT) + tid;
        if (node < n) deg[node] = dg;
    }
    __syncthreads();
    int nbase = b << SHIFT;
    for (int i2 = tid; i2 < NPB * 16; i2 += 512) {
        int nl = i2 >> 4;
        int node = nbase + nl;
        if (node < n) {
            float dn = sdinv[nl];
            size_t gi = (size_t)node * 16 + (i2 & 15);
            float4 vx = ((const float4*)x)[gi];
            __half2 a = __floats2half2_rn(vx.x * dn, vx.y * dn);
            __half2 c = __floats2half2_rn(vx.z * dn, vx.w * dn);
            ((__half2*)xs)[gi * 2 + 0] = a;
            ((__half2*)xs)[gi * 2 + 1] = c;
        }
    }
}

// one block per 128-node bucket. Counting sort INTO LDS (window read once):
// deg row -> scan -> cursor scatter into csrl[CAPB]. Then register gather:
// wave w owns 16 nodes; lane = (edge_group 0..7) x (16B chunk 0..7); edge
// indices read via conflict-free LDS broadcast. fp16 accumulate, bf16 out.
__global__ __launch_bounds__(512) void bucket_gather_kernel(
    const int* __restrict__ staging,
    const int* __restrict__ gcur,
    const int* __restrict__ deg,
    const __half* __restrict__ xs,
    ushort* __restrict__ aggb, int n, int B) {
    int b   = blockIdx.x;
    int tid = threadIdx.x;
    __shared__ int   csrl[CAPB];
    __shared__ int   sstart[NPB];
    __shared__ int   ncur[NPB];
    __shared__ int   sdeg[NPB];
    __shared__ int   ssc[NPB];
    __shared__ float sdinv[NPB];
    int node0 = b << SHIFT;
    int count = gcur[b];
    if (count > CAPB) count = CAPB;
    size_t base = (size_t)b * CAPB;
    if (tid < NPB) {
        int nodeid = node0 + tid;
        int dg = (nodeid < n) ? deg[nodeid] : 0;
        sdeg[tid] = dg;
        ssc[tid]  = dg;
        sdinv[tid] = rsqrtf((float)dg + 1.0f);
    }
    __syncthreads();
    for (int off = 1; off < NPB; off <<= 1) {
        int t = 0;
        if (tid < NPB && tid >= off) t = ssc[tid - off];
        __syncthreads();
        if (tid < NPB) ssc[tid] += t;
        __syncthreads();
    }
    if (tid < NPB) {
        int excl = ssc[tid] - sdeg[tid];
        sstart[tid] = excl;
        ncur[tid]   = excl;
    }
    __syncthreads();
    // counting-sort scatter: one coalesced staging pass, LDS stores only
    for (int i = tid; i < count; i += 512) {
        int p = staging[base + i];
        int pos = atomicAdd(&ncur[p >> 17], 1);
        if (pos < CAPB) csrl[pos] = p & 0x1FFFF;
    }
    __syncthreads();
    // register gather (identical numerics to the R16 gather kernel)
    int wv = tid >> 6, lane = tid & 63;
    int eg = lane >> 3;      // edge group 0..7
    int c  = lane & 7;       // 16B chunk (8 halfs)
    for (int t16 = 0; t16 < 16; ++t16) {
        int nl   = (wv << 4) + t16;
        int node = node0 + nl;
        int s0 = sstart[nl];
        int d  = sdeg[nl];
        __half2 hz = __float2half2_rn(0.f);
        __half2 hacc[4] = {hz, hz, hz, hz};
        int full = d & ~15;
        for (int be = 0; be < full; be += 16) {
            int qb = s0 + be;
            if (qb > CAPB - 16) qb = CAPB - 16;    // safety clamp, never binds
            int i0 = csrl[qb + eg];
            int i1 = csrl[qb + 8 + eg];
            union { uint4 u; __half2 h[4]; } p0, p1;
            p0.u = *(const uint4*)(xs + (size_t)i0 * 64 + c * 8);
            p1.u = *(const uint4*)(xs + (size_t)i1 * 64 + c * 8);
#pragma unroll
            for (int t = 0; t < 4; ++t) hacc[t] = __hadd2(hacc[t], p0.h[t]);
#pragma unroll
            for (int t = 0; t < 4; ++t) hacc[t] = __hadd2(hacc[t], p1.h[t]);
        }
        if (full < d) {   // ragged tail (< 16 edges)
            int e0 = full + eg;
            int e1 = full + 8 + eg;
            int q0 = s0 + (e0 < d ? e0 : d - 1);
            int q1 = s0 + (e1 < d ? e1 : d - 1);
            if (q0 > CAPB - 1) q0 = CAPB - 1;
            if (q1 > CAPB - 1) q1 = CAPB - 1;
            int i0 = csrl[q0];
            int i1 = csrl[q1];
            union { uint4 u; __half2 h[4]; } p0, p1;
            p0.u = *(const uint4*)(xs + (size_t)i0 * 64 + c * 8);
            p1.u = *(const uint4*)(xs + (size_t)i1 * 64 + c * 8);
            if (e0 >= d) p0.u = make_uint4(0u, 0u, 0u, 0u);
            if (e1 >= d) p1.u = make_uint4(0u, 0u, 0u, 0u);
#pragma unroll
            for (int t = 0; t < 4; ++t) hacc[t] = __hadd2(hacc[t], p0.h[t]);
#pragma unroll
            for (int t = 0; t < 4; ++t) hacc[t] = __hadd2(hacc[t], p1.h[t]);
        }
        // packed cross-lane reduce of the 8 edge groups down to eg==0
#pragma unroll
        for (int off = 32; off >= 8; off >>= 1) {
#pragma unroll
            for (int t = 0; t < 4; ++t) {
                union { __half2 h; int i; } u;
                u.h = hacc[t];
                u.i = __shfl_down(u.i, off);
                hacc[t] = __hadd2(hacc[t], u.h);
            }
        }
        if (eg == 0 && node < n) {
            float dn = sdinv[nl];
            union { uint4 u; __half2 h[4]; } p;
            p.u = *(const uint4*)(xs + (size_t)node * 64 + c * 8);
            uint4 o;
            unsigned* ow = (unsigned*)&o;
#pragma unroll
            for (int t = 0; t < 4; ++t) {
                float2 a = __half22float2(hacc[t]);
                float2 f = __half22float2(p.h[t]);
                float v0 = dn * fmaf(f.x, dn, a.x);
                float v1 = dn * fmaf(f.y, dn, a.y);
                ow[t] = (unsigned)f2b(v0) | ((unsigned)f2b(v1) << 16);
            }
            ((uint4*)(aggb + (size_t)node * 64))[c] = o;
        }
    }
}

// 512 threads = 8 waves. Wave w owns cols w*32..w*32+31 for BOTH gates
// (z and ht meet in-register, h=relu((1-z)*ht) -> one h-plane in LDS).
__global__ __launch_bounds__(512) void node_mfma_kernel(
    const ushort* __restrict__ aggb,   // [n][64] bf16
    const ushort* __restrict__ Mb,     // [512][64] bf16 (B layout)
    const float* __restrict__ cb,      // [512]
    const float* __restrict__ Wo, const float* __restrict__ bo,
    float* __restrict__ out, int n) {
    int tid  = threadIdx.x;
    int w    = tid >> 6;
    int lane = tid & 63;
    int nidx = lane & 15;
    int quad = lane >> 4;
    short8 bfz[2][2], bfh[2][2];
    float cbz[2], cbh[2];
#pragma unroll
    for (int cg = 0; cg < 2; ++cg) {
        int colZ = (w << 5) + (cg << 4) + nidx;
        int colH = 256 + colZ;
#pragma unroll
        for (int s = 0; s < 2; ++s) {
            bfz[cg][s] = *(const short8*)(Mb + colZ * 64 + s * 32 + quad * 8);
            bfh[cg][s] = *(const short8*)(Mb + colH * 64 + s * 32 + quad * 8);
        }
        cbz[cg] = cb[colZ];
        cbh[cg] = cb[colH];
    }
    __shared__ float sH[32][260];    // 33 KB h-plane (260 pad: 2-way on stores)
    __shared__ float sWo[4][256];
    if (tid < 256) {
#pragma unroll
        for (int o = 0; o < 4; ++o) sWo[o][tid] = Wo[tid * 4 + o];
    }
    float bo0 = bo[0], bo1 = bo[1], bo2 = bo[2], bo3 = bo[3];
    int ntiles = (n + 31) >> 5;
    for (int tile = blockIdx.x; tile < ntiles; tile += gridDim.x) {
        int node0 = tile << 5;
        int nA0 = node0 + nidx;
        int nA1 = node0 + 16 + nidx;
        if (nA0 >= n) nA0 = n - 1;   // clamp; stores are guarded
        if (nA1 >= n) nA1 = n - 1;
        const ushort* ar0 = aggb + (size_t)nA0 * 64;
        const ushort* ar1 = aggb + (size_t)nA1 * 64;
        short8 a00 = *(const short8*)(ar0 + quad * 8);
        short8 a01 = *(const short8*)(ar0 + 32 + quad * 8);
        short8 a10 = *(const short8*)(ar1 + quad * 8);
        short8 a11 = *(const short8*)(ar1 + 32 + quad * 8);
#pragma unroll
        for (int cg = 0; cg < 2; ++cg) {
            int col = (w << 5) + (cg << 4) + nidx;
#pragma unroll
            for (int grp = 0; grp < 2; ++grp) {
                short8 a0 = grp ? a10 : a00;
                short8 a1 = grp ? a11 : a01;
                floatx4 cz = {cbz[cg], cbz[cg], cbz[cg], cbz[cg]};
                cz = __builtin_amdgcn_mfma_f32_16x16x32_bf16(a0, bfz[cg][0], cz, 0, 0, 0);
                cz = __builtin_amdgcn_mfma_f32_16x16x32_bf16(a1, bfz[cg][1], cz, 0, 0, 0);
                floatx4 chh = {cbh[cg], cbh[cg], cbh[cg], cbh[cg]};
                chh = __builtin_amdgcn_mfma_f32_16x16x32_bf16(a0, bfh[cg][0], chh, 0, 0, 0);
                chh = __builtin_amdgcn_mfma_f32_16x16x32_bf16(a1, bfh[cg][1], chh, 0, 0, 0);
#pragma unroll
                for (int r = 0; r < 4; ++r) {
                    int row = (grp << 4) + (quad << 2) + r;   // node within tile
                    float zc = fastrcp(1.0f + __expf(cz[r]));     // 1 - sigmoid
                    float th = 1.0f - 2.0f * fastrcp(1.0f + __expf(2.0f * chh[r]));
                    sH[row][col] = fmaxf(zc * th, 0.0f);
                }
            }
        }
        __syncthreads();
        {   // head: 16 threads per node, 16 channels each
            int nb = tid >> 4, g = tid & 15;
            float l0 = 0.f, l1 = 0.f, l2 = 0.f, l3 = 0.f;
#pragma unroll
            for (int ii = 0; ii < 16; ++ii) {
                int ch = g + 16 * ii;
                float hv = sH[nb][ch];
                l0 = fmaf(hv, sWo[0][ch], l0);
                l1 = fmaf(hv, sWo[1][ch], l1);
                l2 = fmaf(hv, sWo[2][ch], l2);
                l3 = fmaf(hv, sWo[3][ch], l3);
            }
#pragma unroll
            for (int off = 8; off > 0; off >>= 1) {
                l0 += __shfl_down(l0, off, 16);
                l1 += __shfl_down(l1, off, 16);
                l2 += __shfl_down(l2, off, 16);
                l3 += __shfl_down(l3, off, 16);
            }
            int node = node0 + nb;
            if (g == 0 && node < n) {
                float v0 = l0 + bo0, v1 = l1 + bo1, v2 = l2 + bo2, v3 = l3 + bo3;
                float mx = fmaxf(fmaxf(v0, v1), fmaxf(v2, v3));
                float e0 = __expf(v0 - mx), e1 = __expf(v1 - mx);
                float e2 = __expf(v2 - mx), e3 = __expf(v3 - mx);
                float inv = fastrcp(e0 + e1 + e2 + e3);
                float4 o;
                o.x = e0 * inv; o.y = e1 * inv; o.z = e2 * inv; o.w = e3 * inv;
                ((float4*)out)[node] = o;
            }
        }
        __syncthreads();
    }
}

extern "C" void kernel_launch(void* const* d_in, const int* in_sizes, int n_in,
                              void* d_out, int out_size, void* d_ws, size_t ws_size,
                              hipStream_t stream) {
    const float* x   = (const float*)d_in[0];
    const int*  eidx = (const int*)d_in[1];
    const float* Wz  = (const float*)d_in[2];
    const float* bz  = (const float*)d_in[3];
    // d_in[4]=Wr, d_in[5]=br : dead (H0 = 0)
    const float* Wh  = (const float*)d_in[6];
    const float* bh  = (const float*)d_in[7];
    const float* Lzw = (const float*)d_in[8];
    const float* Lzb = (const float*)d_in[9];
    // d_in[10]=Lrw, d_in[11]=Lrb : dead
    const float* Lhw = (const float*)d_in[12];
    const float* Lhb = (const float*)d_in[13];
    const float* Wo  = (const float*)d_in[14];
    const float* bo  = (const float*)d_in[15];
    float* out = (float*)d_out;

    int n = in_sizes[0] / 64;
    int E = in_sizes[1] / 2;
    const int* srcs = eidx;
    const int* dsts = eidx + E;
    int B = (n + NPB - 1) >> SHIFT;
    int nT = (E + TILE - 1) / TILE;

    size_t na = ((size_t)n + 3) & ~(size_t)3;
    size_t stageBytes = (((size_t)B * CAPB * 4) + 255) & ~(size_t)255;
    size_t aggBytes   = (((size_t)n * 64 * 2) + 255) & ~(size_t)255;

    char* ws = (char*)d_ws;
    int*   deg   = (int*)ws;    ws += na * 4;
    int*   gcur  = (int*)ws;    ws += BMAX * 4;
    int*   staging = (int*)ws;  ws += stageBytes;       // live through gather
    __half* xs   = (__half*)ws; ws += (size_t)n * 64 * 2;
    ushort* aggb = (ushort*)ws; ws += aggBytes;
    ushort* Mb   = (ushort*)ws; ws += 512 * 64 * 2;
    float* cb    = (float*)ws;  ws += 512 * 4;

    hipMemsetAsync(gcur, 0, BMAX * 4, stream);
    scatter_build_kernel<<<nT + MBBLK, 512, 0, stream>>>(srcs, dsts, gcur,
                                                         staging, E, B, nT,
                                                         Wz, bz, Wh, bh,
                                                         Lzw, Lzb, Lhw, Lhb,
                                                         Mb, cb);
    prep_kernel<<<B, 512, 0, stream>>>(staging, gcur, x, deg, xs, n, B);
    bucket_gather_kernel<<<B, 512, 0, stream>>>(staging, gcur, deg,
                                                xs, aggb, n, B);
    node_mfma_kernel<<<1024, 512, 0, stream>>>(aggb, Mb, cb, Wo, bo, out, n);
}